// Round 4
// baseline (389.117 us; speedup 1.0000x reference)
//
#include <hip/hip_runtime.h>
#include <hip/hip_bf16.h>

// W8Linear: out[32,16384] = (x[32,4096] . W[16384,4096]^T) * scale[n] + bias[n]
// Harness dtype reality (forensically confirmed rounds 0-3):
//   x/scale/bias: fp32 buffers (fp16 promoted); weight: int32 (268 MB);
//   out: FLOAT32 (fp16 maps to "else float*"). Round 3 passed (absmax 2.0).
// Round 4: perf. R3 kernel ran ~145 us (1.85 TB/s weight stream) at 1 wave/SIMD.
// This round: 16 waves/CU via split-K x4 + pre-converted bf16 x + reduce kernel.
//   k1 xcvt:   x fp32 -> bf16 row-major [32][4096] in d_ws (256 KB)
//   k2 gemm:   grid 1024 (=256 ch-groups x 4 k-splits), 4 waves/block,
//              wave = 16 ch x 32 tok x 1024 k, partials fp32 -> d_ws+256K (8 MB)
//   k3 reduce: sum 4 partials, *scale + bias, fp32 out.

typedef __attribute__((ext_vector_type(4))) int    i32x4;
typedef __attribute__((ext_vector_type(4))) float  f32x4;
typedef __attribute__((ext_vector_type(8))) short  s16x8;
typedef __attribute__((ext_vector_type(8))) __bf16 bf16x8;

constexpr int K = 4096;
constexpr int N = 16384;
constexpr int T = 32;
constexpr int KSPLIT = 4;
constexpr int KPW = K / KSPLIT;          // 1024 k per wave
constexpr size_t XB_OFF = 0;             // bf16 x: 32*4096*2 = 256 KB
constexpr size_t PART_OFF = 262144;      // partials: 4*32*16384*4 = 8 MB

// fp32 -> bf16 RNE (finite inputs).
__device__ inline unsigned short f2bf_rne(float f) {
    unsigned u = __builtin_bit_cast(unsigned, f);
    u += 0x7FFF + ((u >> 16) & 1);
    return (unsigned short)(u >> 16);
}

// 8 int32 weights -> 8 bf16, exact (|w|<=127; fp32->bf16 truncation lossless).
__device__ inline bf16x8 cvtW(i32x4 lo, i32x4 hi) {
    s16x8 r;
#pragma unroll
    for (int i = 0; i < 4; ++i) {
        r[i]     = (short)(__builtin_bit_cast(unsigned, (float)lo[i]) >> 16);
        r[i + 4] = (short)(__builtin_bit_cast(unsigned, (float)hi[i]) >> 16);
    }
    return __builtin_bit_cast(bf16x8, r);
}

// ---- k1: x fp32 -> bf16 ----------------------------------------------------
__global__ __launch_bounds__(256) void xcvt_kernel(const float* __restrict__ x,
                                                   unsigned short* __restrict__ xb) {
    const int i = (blockIdx.x * 256 + threadIdx.x) * 8;   // 16384 threads * 8 = 131072
    f32x4 lo = *reinterpret_cast<const f32x4*>(x + i);
    f32x4 hi = *reinterpret_cast<const f32x4*>(x + i + 4);
    s16x8 r;
#pragma unroll
    for (int j = 0; j < 4; ++j) {
        r[j]     = (short)f2bf_rne(lo[j]);
        r[j + 4] = (short)f2bf_rne(hi[j]);
    }
    *reinterpret_cast<s16x8*>(xb + i) = r;
}

// ---- k2: split-K GEMM ------------------------------------------------------
__global__ __launch_bounds__(256, 4) void w8gemm_kernel(
    const __bf16* __restrict__ xb,
    const int* __restrict__ w,
    float* __restrict__ partial)
{
    const int lane = threadIdx.x & 63;
    const int wave = threadIdx.x >> 6;
    const int n16  = lane & 15;
    const int quad = lane >> 4;

    const int g  = blockIdx.x & 255;   // channel group
    const int ks = blockIdx.x >> 8;    // k-split 0..3

    const int c = g * 64 + wave * 16 + n16;
    const int k0 = ks * KPW;

    const int*   __restrict__ wrow = w + (size_t)c * K + k0;
    const __bf16* __restrict__ xr0 = xb + (size_t)n16 * K + k0;          // tokens 0..15
    const __bf16* __restrict__ xr1 = xb + (size_t)(n16 + 16) * K + k0;   // tokens 16..31

    f32x4 acc0 = {0.f, 0.f, 0.f, 0.f};
    f32x4 acc1 = {0.f, 0.f, 0.f, 0.f};

    // chunk = 64 k (2 mfma steps); double buffered. ~100 VGPR live set.
    i32x4 bA[4], bB[4];
    bf16x8 aA[4], aB[4];

    auto load_chunk = [&](int kc, i32x4* bb, bf16x8* aa) {
        const int e0 = kc + quad * 8;        // step 0 element offset
        const int e1 = e0 + 32;              // step 1
        bb[0] = *reinterpret_cast<const i32x4*>(wrow + e0);
        bb[1] = *reinterpret_cast<const i32x4*>(wrow + e0 + 4);
        bb[2] = *reinterpret_cast<const i32x4*>(wrow + e1);
        bb[3] = *reinterpret_cast<const i32x4*>(wrow + e1 + 4);
        aa[0] = *reinterpret_cast<const bf16x8*>(xr0 + e0);
        aa[1] = *reinterpret_cast<const bf16x8*>(xr1 + e0);
        aa[2] = *reinterpret_cast<const bf16x8*>(xr0 + e1);
        aa[3] = *reinterpret_cast<const bf16x8*>(xr1 + e1);
    };
    auto compute_chunk = [&](const i32x4* bb, const bf16x8* aa) {
        bf16x8 bf0 = cvtW(bb[0], bb[1]);
        acc0 = __builtin_amdgcn_mfma_f32_16x16x32_bf16(aa[0], bf0, acc0, 0, 0, 0);
        acc1 = __builtin_amdgcn_mfma_f32_16x16x32_bf16(aa[1], bf0, acc1, 0, 0, 0);
        bf16x8 bf1 = cvtW(bb[2], bb[3]);
        acc0 = __builtin_amdgcn_mfma_f32_16x16x32_bf16(aa[2], bf1, acc0, 0, 0, 0);
        acc1 = __builtin_amdgcn_mfma_f32_16x16x32_bf16(aa[3], bf1, acc1, 0, 0, 0);
    };

    load_chunk(0, bA, aA);
#pragma unroll 1
    for (int kc = 0; kc < KPW; kc += 128) {
        load_chunk(kc + 64, bB, aB);
        compute_chunk(bA, aA);
        if (kc + 128 < KPW) load_chunk(kc + 128, bA, aA);
        compute_chunk(bB, aB);
    }

    // partial[ks][token][channel]; D layout: col = lane&15, row = quad*4 + v.
    float* __restrict__ p = partial + (size_t)ks * T * N;
#pragma unroll
    for (int v = 0; v < 4; ++v) {
        const int row = quad * 4 + v;
        p[(size_t)row * N + c]        = acc0[v];
        p[(size_t)(row + 16) * N + c] = acc1[v];
    }
}

// ---- k3: reduce + scale + bias --------------------------------------------
__global__ __launch_bounds__(256) void reduce_kernel(
    const float* __restrict__ partial,
    const float* __restrict__ scale,
    const float* __restrict__ bias,
    float* __restrict__ out)
{
    const int i = (blockIdx.x * 256 + threadIdx.x) * 4;  // over 32*16384 outs
    const int c = i & (N - 1);                            // N power of 2
    f32x4 s = *reinterpret_cast<const f32x4*>(partial + i);
#pragma unroll
    for (int ks = 1; ks < KSPLIT; ++ks) {
        f32x4 pv = *reinterpret_cast<const f32x4*>(partial + (size_t)ks * T * N + i);
        s[0] += pv[0]; s[1] += pv[1]; s[2] += pv[2]; s[3] += pv[3];
    }
    f32x4 sc = *reinterpret_cast<const f32x4*>(scale + c);
    f32x4 bi = *reinterpret_cast<const f32x4*>(bias + c);
    f32x4 r = {s[0] * sc[0] + bi[0], s[1] * sc[1] + bi[1],
               s[2] * sc[2] + bi[2], s[3] * sc[3] + bi[3]};
    *reinterpret_cast<f32x4*>(out + i) = r;
}

extern "C" void kernel_launch(void* const* d_in, const int* in_sizes, int n_in,
                              void* d_out, int out_size, void* d_ws, size_t ws_size,
                              hipStream_t stream) {
    const float* x     = (const float*)d_in[0];
    const int*   w     = (const int*)d_in[1];
    const float* scale = (const float*)d_in[2];
    const float* bias  = (const float*)d_in[3];
    float* out = (float*)d_out;

    unsigned short* xb = (unsigned short*)((char*)d_ws + XB_OFF);
    float* part        = (float*)((char*)d_ws + PART_OFF);

    xcvt_kernel<<<dim3(64), dim3(256), 0, stream>>>(x, xb);                       // 131072/8/256
    w8gemm_kernel<<<dim3(256 * KSPLIT), dim3(256), 0, stream>>>(
        (const __bf16*)xb, w, part);
    reduce_kernel<<<dim3((T * N / 4) / 256), dim3(256), 0, stream>>>(
        part, scale, bias, out);
}

// Round 5
// 383.157 us; speedup vs baseline: 1.0156x; 1.0156x over previous
//
#include <hip/hip_runtime.h>
#include <hip/hip_bf16.h>

// W8Linear: out[32,16384] = (x[32,4096] . W[16384,4096]^T) * scale[n] + bias[n]
// Harness dtype reality (forensically confirmed rounds 0-3):
//   x/scale/bias: fp32 buffers (fp16 promoted); weight: int32 (268 MB);
//   out: FLOAT32. Correctness validated round 3/4 (absmax 2.0).
// Perf history: R3 (1 wave/SIMD, reg-resident) GEMM ~145us = 1.85 TB/s weight
// stream. R4 (split-K x4, 16 waves/CU, bf16 x) IDENTICAL ~145us -> NOT
// occupancy/latency bound. Invariant = address pattern: each load touches 16
// rows @16KB stride, 128B/row -> DRAM page-miss bound (~1/3 of stream BW).
// R5: stage weights via global_load_lds, 1KB CONTIGUOUS per instruction from a
// single row; MFMA reads from padded LDS. 64 rows x 256 ints/tile = 64KB LDS
// (+16B/row pad), single-buffered, 2 blocks/CU, split-K x2 (grid 512).
//   k1 xcvt:   x fp32 -> bf16 [32][4096] in d_ws (256 KB)
//   k2 gemm:   grid 512 (=256 ch-groups x 2 k-splits), 4 waves, partials fp32
//   k3 reduce: sum 2 partials, *scale + bias, fp32 out.

typedef __attribute__((ext_vector_type(4))) int    i32x4;
typedef __attribute__((ext_vector_type(4))) float  f32x4;
typedef __attribute__((ext_vector_type(8))) short  s16x8;
typedef __attribute__((ext_vector_type(8))) __bf16 bf16x8;

constexpr int K = 4096;
constexpr int N = 16384;
constexpr int T = 32;
constexpr int KSPLIT = 2;
constexpr int KPW = K / KSPLIT;            // 2048 k per block
constexpr int BK = 256;                    // k-elements per LDS tile (1KB/row)
constexpr int NT = KPW / BK;               // 8 tiles
constexpr int ROWPITCH = 1024 + 16;        // bytes; +16 pad -> 2-way LDS banking (free)
constexpr size_t XB_OFF = 0;               // bf16 x: 32*4096*2 = 256 KB
constexpr size_t PART_OFF = 262144;        // partials: 2*32*16384*4 = 4 MB

// fp32 -> bf16 RNE (finite inputs).
__device__ inline unsigned short f2bf_rne(float f) {
    unsigned u = __builtin_bit_cast(unsigned, f);
    u += 0x7FFF + ((u >> 16) & 1);
    return (unsigned short)(u >> 16);
}

// 8 int32 weights -> 8 bf16, exact (|w|<=127; fp32->bf16 truncation lossless).
__device__ inline bf16x8 cvtW(i32x4 lo, i32x4 hi) {
    s16x8 r;
#pragma unroll
    for (int i = 0; i < 4; ++i) {
        r[i]     = (short)(__builtin_bit_cast(unsigned, (float)lo[i]) >> 16);
        r[i + 4] = (short)(__builtin_bit_cast(unsigned, (float)hi[i]) >> 16);
    }
    return __builtin_bit_cast(bf16x8, r);
}

// ---- k1: x fp32 -> bf16 ----------------------------------------------------
__global__ __launch_bounds__(256) void xcvt_kernel(const float* __restrict__ x,
                                                   unsigned short* __restrict__ xb) {
    const int i = (blockIdx.x * 256 + threadIdx.x) * 8;
    f32x4 lo = *reinterpret_cast<const f32x4*>(x + i);
    f32x4 hi = *reinterpret_cast<const f32x4*>(x + i + 4);
    s16x8 r;
#pragma unroll
    for (int j = 0; j < 4; ++j) {
        r[j]     = (short)f2bf_rne(lo[j]);
        r[j + 4] = (short)f2bf_rne(hi[j]);
    }
    *reinterpret_cast<s16x8*>(xb + i) = r;
}

// ---- k2: split-K GEMM, LDS-staged contiguous weight stream -----------------
__global__ __launch_bounds__(256, 2) void w8gemm_kernel(
    const __bf16* __restrict__ xb,
    const int* __restrict__ w,
    float* __restrict__ partial)
{
    extern __shared__ char smem[];   // 64 * ROWPITCH = 66560 B

    const int lane = threadIdx.x & 63;
    const int wave = threadIdx.x >> 6;
    const int n16  = lane & 15;
    const int quad = lane >> 4;

    const int g  = blockIdx.x & 255;   // channel group (64 rows)
    const int ks = blockIdx.x >> 8;    // k-split 0..1
    const int kbase = ks * KPW;

    // Wave stages its own 16 rows: one instruction = 1KB contiguous from 1 row.
    const char* gW0 = (const char*)w
        + ((size_t)(g * 64 + wave * 16) * K + kbase) * 4 + (size_t)lane * 16;
    char* lds0 = smem + (wave * 16) * ROWPITCH + lane * 16;

    auto stage = [&](int it) {
        const char* gp = gW0 + (size_t)it * BK * 4;
#pragma unroll
        for (int j = 0; j < 16; ++j) {
            __builtin_amdgcn_global_load_lds(
                (const __attribute__((address_space(1))) void*)(gp + (size_t)j * K * 4),
                (__attribute__((address_space(3))) void*)(lds0 + j * ROWPITCH),
                16, 0, 0);
        }
    };

    // x fragments: A[m=lane&15][k=quad*8+j]; tokens n16 (acc0) and n16+16 (acc1).
    const __bf16* __restrict__ xr0 = xb + (size_t)n16 * K + kbase + quad * 8;
    const __bf16* __restrict__ xr1 = xr0 + (size_t)16 * K;

    f32x4 acc0 = {0.f, 0.f, 0.f, 0.f};
    f32x4 acc1 = {0.f, 0.f, 0.f, 0.f};

    // LDS read base for this lane's B fragment (row = wave*16 + n16).
    const char* lrow = smem + (wave * 16 + n16) * ROWPITCH + quad * 32;

    stage(0);
#pragma unroll 1
    for (int it = 0; it < NT; ++it) {
        // Prefetch this tile's x fragments to registers (L2-hot, 16 x 16B).
        bf16x8 aX0[8], aX1[8];
#pragma unroll
        for (int s = 0; s < 8; ++s) {
            const int off = it * BK + s * 32;
            aX0[s] = *reinterpret_cast<const bf16x8*>(xr0 + off);
            aX1[s] = *reinterpret_cast<const bf16x8*>(xr1 + off);
        }
        __syncthreads();   // staging (and x loads) complete
#pragma unroll
        for (int s = 0; s < 8; ++s) {
            i32x4 b0 = *reinterpret_cast<const i32x4*>(lrow + s * 128);
            i32x4 b1 = *reinterpret_cast<const i32x4*>(lrow + s * 128 + 16);
            bf16x8 bf = cvtW(b0, b1);
            acc0 = __builtin_amdgcn_mfma_f32_16x16x32_bf16(aX0[s], bf, acc0, 0, 0, 0);
            acc1 = __builtin_amdgcn_mfma_f32_16x16x32_bf16(aX1[s], bf, acc1, 0, 0, 0);
        }
        __syncthreads();   // all reads done before restaging the buffer
        if (it + 1 < NT) stage(it + 1);
    }

    // partial[ks][token][channel]; D layout: col = lane&15, row = quad*4 + v.
    const int c = g * 64 + wave * 16 + n16;
    float* __restrict__ p = partial + (size_t)ks * T * N;
#pragma unroll
    for (int v = 0; v < 4; ++v) {
        const int row = quad * 4 + v;
        p[(size_t)row * N + c]        = acc0[v];
        p[(size_t)(row + 16) * N + c] = acc1[v];
    }
}

// ---- k3: reduce + scale + bias --------------------------------------------
__global__ __launch_bounds__(256) void reduce_kernel(
    const float* __restrict__ partial,
    const float* __restrict__ scale,
    const float* __restrict__ bias,
    float* __restrict__ out)
{
    const int i = (blockIdx.x * 256 + threadIdx.x) * 4;
    const int c = i & (N - 1);
    f32x4 s = *reinterpret_cast<const f32x4*>(partial + i);
#pragma unroll
    for (int ks = 1; ks < KSPLIT; ++ks) {
        f32x4 pv = *reinterpret_cast<const f32x4*>(partial + (size_t)ks * T * N + i);
        s[0] += pv[0]; s[1] += pv[1]; s[2] += pv[2]; s[3] += pv[3];
    }
    f32x4 sc = *reinterpret_cast<const f32x4*>(scale + c);
    f32x4 bi = *reinterpret_cast<const f32x4*>(bias + c);
    f32x4 r = {s[0] * sc[0] + bi[0], s[1] * sc[1] + bi[1],
               s[2] * sc[2] + bi[2], s[3] * sc[3] + bi[3]};
    *reinterpret_cast<f32x4*>(out + i) = r;
}

extern "C" void kernel_launch(void* const* d_in, const int* in_sizes, int n_in,
                              void* d_out, int out_size, void* d_ws, size_t ws_size,
                              hipStream_t stream) {
    const float* x     = (const float*)d_in[0];
    const int*   w     = (const int*)d_in[1];
    const float* scale = (const float*)d_in[2];
    const float* bias  = (const float*)d_in[3];
    float* out = (float*)d_out;

    unsigned short* xb = (unsigned short*)((char*)d_ws + XB_OFF);
    float* part        = (float*)((char*)d_ws + PART_OFF);

    xcvt_kernel<<<dim3(64), dim3(256), 0, stream>>>(x, xb);
    w8gemm_kernel<<<dim3(256 * KSPLIT), dim3(256), 64 * ROWPITCH, stream>>>(
        (const __bf16*)xb, w, part);
    reduce_kernel<<<dim3((T * N / 4) / 256), dim3(256), 0, stream>>>(
        part, scale, bias, out);
}